// Round 1
// baseline (1521.175 us; speedup 1.0000x reference)
//
#include <hip/hip_runtime.h>

// ---------------- dims ----------------
#define BB 1024
#define NN 9
#define LL 81            // 81 cells
#define DD 512
#define HH 8
#define EE 64
#define FF 2048
#define MM (BB*LL)       // 82944 rows
#define N3 (3*DD)        // 1536

typedef unsigned short u16;
typedef __bf16 bf16x8 __attribute__((ext_vector_type(8)));
typedef float f32x4 __attribute__((ext_vector_type(4)));
typedef unsigned short u16x8 __attribute__((ext_vector_type(8)));

__device__ __forceinline__ float bf2f(u16 u) {
    return __uint_as_float(((unsigned int)u) << 16);
}
__device__ __forceinline__ u16 f2bf(float f) {
    unsigned int u = __float_as_uint(f);
    unsigned int r = u + 0x7fffu + ((u >> 16) & 1u);
    return (u16)(r >> 16);
}
__device__ __forceinline__ float gelu_exact(float v) {
    return 0.5f * v * (1.0f + erff(v * 0.70710678118654752f));
}

// ---------------- weight transpose + fp32->bf16 ----------------
// W: K x N row-major fp32  ->  Wt: N x K row-major bf16
__global__ void transpose_w(const float* __restrict__ W, u16* __restrict__ Wt,
                            int K, int N) {
    __shared__ float t[32][33];
    int n0 = blockIdx.x * 32, k0 = blockIdx.y * 32;
    int tx = threadIdx.x & 31, ty = threadIdx.x >> 5;  // 32 x 8
#pragma unroll
    for (int i = 0; i < 32; i += 8)
        t[ty + i][tx] = W[(long)(k0 + ty + i) * N + n0 + tx];
    __syncthreads();
#pragma unroll
    for (int i = 0; i < 32; i += 8)
        Wt[(long)(n0 + ty + i) * K + k0 + tx] = f2bf(t[tx][ty + i]);
}

// ---------------- layernorm (fp32 in -> bf16 out), one wave per 512-row ----------------
__global__ __launch_bounds__(256) void layernorm_k(const float* __restrict__ X,
                                                   const float* __restrict__ g,
                                                   const float* __restrict__ be,
                                                   u16* __restrict__ Y) {
    int row = blockIdx.x * 4 + (threadIdx.x >> 6);
    int lane = threadIdx.x & 63;
    const float4* xp = (const float4*)(X + (long)row * DD);
    float4 a = xp[lane * 2], b = xp[lane * 2 + 1];
    float s  = a.x + a.y + a.z + a.w + b.x + b.y + b.z + b.w;
    float sq = a.x*a.x + a.y*a.y + a.z*a.z + a.w*a.w
             + b.x*b.x + b.y*b.y + b.z*b.z + b.w*b.w;
#pragma unroll
    for (int off = 1; off < 64; off <<= 1) {
        s  += __shfl_xor(s, off);
        sq += __shfl_xor(sq, off);
    }
    float mean = s * (1.0f / 512.0f);
    float var  = sq * (1.0f / 512.0f) - mean * mean;
    float rstd = rsqrtf(var + 1e-5f);
    const float4* gp = (const float4*)(g + lane * 8);
    const float4* bp = (const float4*)(be + lane * 8);
    float4 g0 = gp[0], g1v = gp[1], b0 = bp[0], b1v = bp[1];
    float xv[8] = {a.x,a.y,a.z,a.w,b.x,b.y,b.z,b.w};
    float gv[8] = {g0.x,g0.y,g0.z,g0.w,g1v.x,g1v.y,g1v.z,g1v.w};
    float bv[8] = {b0.x,b0.y,b0.z,b0.w,b1v.x,b1v.y,b1v.z,b1v.w};
    u16x8 ov;
#pragma unroll
    for (int j = 0; j < 8; ++j)
        ov[j] = f2bf((xv[j] - mean) * rstd * gv[j] + bv[j]);
    *(u16x8*)(Y + (long)row * DD + lane * 8) = ov;
}

// ---------------- GEMM: C = A(bf16, MxK) @ Bt^T(bf16, NxK) with epilogues ----------------
enum { EPI_BF16_BIAS = 0, EPI_F32_RESID = 1, EPI_BF16_GELU = 2, EPI_F32_ACCUM = 3 };

template <int EPI>
__global__ __launch_bounds__(256, 2) void gemm_bt(
    const u16* __restrict__ A, int lda,
    const u16* __restrict__ Bt, int ldb,
    const float* __restrict__ bias,   // may be null
    const float* __restrict__ resid,  // EPI_F32_RESID only
    u16* __restrict__ outB, float* __restrict__ outF,
    int N, int K) {
    __shared__ u16 As[2][128][40];   // 32 k + pad 8
    __shared__ u16 Bs[2][128][40];
    const int tid = threadIdx.x;
    const int lane = tid & 63;
    const int w = tid >> 6;
    const int wr = w >> 1, wc = w & 1;
    const int bm = blockIdx.y, bn = blockIdx.x;
    const long Arow0 = (long)bm * 128;
    const long Brow0 = (long)bn * 128;

    f32x4 acc[4][4] = {};

    const int r = tid >> 2;   // 0..63
    const int s = tid & 3;    // k slot (8 bf16 each)

    const int nk = K / 32;
    u16x8 ra0, ra1, rb0, rb1;
    {
        const u16* ap = A + (Arow0 + r) * (long)lda + s * 8;
        const u16* bp = Bt + (Brow0 + r) * (long)ldb + s * 8;
        ra0 = *(const u16x8*)(ap);
        ra1 = *(const u16x8*)(ap + 64 * (long)lda);
        rb0 = *(const u16x8*)(bp);
        rb1 = *(const u16x8*)(bp + 64 * (long)ldb);
    }
    *(u16x8*)&As[0][r][s * 8] = ra0;
    *(u16x8*)&As[0][r + 64][s * 8] = ra1;
    *(u16x8*)&Bs[0][r][s * 8] = rb0;
    *(u16x8*)&Bs[0][r + 64][s * 8] = rb1;

    for (int kt = 0; kt < nk; ++kt) {
        const int cur = kt & 1, nxt = cur ^ 1;
        __syncthreads();
        if (kt + 1 < nk) {
            const u16* ap = A + (Arow0 + r) * (long)lda + (kt + 1) * 32 + s * 8;
            const u16* bp = Bt + (Brow0 + r) * (long)ldb + (kt + 1) * 32 + s * 8;
            ra0 = *(const u16x8*)(ap);
            ra1 = *(const u16x8*)(ap + 64 * (long)lda);
            rb0 = *(const u16x8*)(bp);
            rb1 = *(const u16x8*)(bp + 64 * (long)ldb);
        }
        bf16x8 af[4], bb[4];
#pragma unroll
        for (int mt = 0; mt < 4; ++mt)
            af[mt] = *(const bf16x8*)&As[cur][wr * 64 + mt * 16 + (lane & 15)][(lane >> 4) * 8];
#pragma unroll
        for (int nt = 0; nt < 4; ++nt)
            bb[nt] = *(const bf16x8*)&Bs[cur][wc * 64 + nt * 16 + (lane & 15)][(lane >> 4) * 8];
#pragma unroll
        for (int mt = 0; mt < 4; ++mt)
#pragma unroll
            for (int nt = 0; nt < 4; ++nt)
                acc[mt][nt] = __builtin_amdgcn_mfma_f32_16x16x32_bf16(af[mt], bb[nt], acc[mt][nt], 0, 0, 0);
        if (kt + 1 < nk) {
            *(u16x8*)&As[nxt][r][s * 8] = ra0;
            *(u16x8*)&As[nxt][r + 64][s * 8] = ra1;
            *(u16x8*)&Bs[nxt][r][s * 8] = rb0;
            *(u16x8*)&Bs[nxt][r + 64][s * 8] = rb1;
        }
    }

    // epilogue
    const int col0 = bn * 128 + wc * 64;
    const int row0 = bm * 128 + wr * 64;
#pragma unroll
    for (int nt = 0; nt < 4; ++nt) {
        const int col = col0 + nt * 16 + (lane & 15);
        const float bv = bias ? bias[col] : 0.0f;
#pragma unroll
        for (int mt = 0; mt < 4; ++mt) {
            const int rowb = row0 + mt * 16 + ((lane >> 4) * 4);
#pragma unroll
            for (int q = 0; q < 4; ++q) {
                const long idx = (long)(rowb + q) * N + col;
                float v = acc[mt][nt][q] + bv;
                if (EPI == EPI_BF16_BIAS) {
                    outB[idx] = f2bf(v);
                } else if (EPI == EPI_F32_RESID) {
                    outF[idx] = v + resid[idx];
                } else if (EPI == EPI_BF16_GELU) {
                    outB[idx] = f2bf(gelu_exact(v));
                } else {  // EPI_F32_ACCUM
                    outF[idx] += v;
                }
            }
        }
    }
}

// ---------------- factorized attention: one workgroup per (b, h) ----------------
// qkv: (B*L, 1536) bf16 ; y: (B*L, 512) bf16
__global__ __launch_bounds__(256) void attn_k(const u16* __restrict__ qkv,
                                              u16* __restrict__ y) {
    __shared__ u16 qs[81][66], ks[81][66], vs[81][66];
    __shared__ float ps[3][81][9];
    const int bh = blockIdx.x;
    const int b = bh >> 3, h = bh & 7;
    const long base = (long)b * LL * N3 + h * EE;
    const int tid = threadIdx.x;

    // load q,k,v for this (b,h) into LDS (81 x 64 each)
    for (int i = tid; i < LL * 16; i += 256) {   // 16 ushort4 per row
        const int l = i >> 4, e0 = (i & 15) * 4;
        const long rowoff = base + (long)l * N3 + e0;
        ushort4 qv = *(const ushort4*)(qkv + rowoff);
        ushort4 kv = *(const ushort4*)(qkv + rowoff + DD);
        ushort4 vv = *(const ushort4*)(qkv + rowoff + 2 * DD);
        qs[l][e0] = qv.x; qs[l][e0+1] = qv.y; qs[l][e0+2] = qv.z; qs[l][e0+3] = qv.w;
        ks[l][e0] = kv.x; ks[l][e0+1] = kv.y; ks[l][e0+2] = kv.z; ks[l][e0+3] = kv.w;
        vs[l][e0] = vv.x; vs[l][e0+1] = vv.y; vs[l][e0+2] = vv.z; vs[l][e0+3] = vv.w;
    }
    __syncthreads();

    // phase 1: scores + softmax.  thread t<243 handles (type, cell)
    if (tid < 243) {
        const int t = tid / 81, cell = tid % 81;
        const int r = cell / 9, c = cell % 9;
        int mm[9];
        if (t == 0) {
#pragma unroll
            for (int j = 0; j < 9; ++j) mm[j] = r * 9 + j;
        } else if (t == 1) {
#pragma unroll
            for (int j = 0; j < 9; ++j) mm[j] = j * 9 + c;
        } else {
            const int br = (r / 3) * 3, bc = (c / 3) * 3;
#pragma unroll
            for (int j = 0; j < 9; ++j) mm[j] = (br + j / 3) * 9 + bc + j % 3;
        }
        float sc[9] = {0, 0, 0, 0, 0, 0, 0, 0, 0};
        for (int e = 0; e < 64; ++e) {
            const float qv = bf2f(qs[cell][e]);
#pragma unroll
            for (int j = 0; j < 9; ++j) sc[j] = fmaf(qv, bf2f(ks[mm[j]][e]), sc[j]);
        }
        float mx = -1e30f;
#pragma unroll
        for (int j = 0; j < 9; ++j) { sc[j] *= 0.125f; mx = fmaxf(mx, sc[j]); }
        float sum = 0.0f;
#pragma unroll
        for (int j = 0; j < 9; ++j) { sc[j] = expf(sc[j] - mx); sum += sc[j]; }
        const float inv = 1.0f / sum;
#pragma unroll
        for (int j = 0; j < 9; ++j) ps[t][cell][j] = sc[j] * inv;
    }
    __syncthreads();

    // phase 2: y = (P_r V + P_c V + P_b V)/3 ; lanes = e dims, wavegroup walks cells
    const int e = tid & 63, wg = tid >> 6;
    for (int k = 0; k < 21; ++k) {
        const int cell = wg + 4 * k;
        if (cell > 80) break;
        const int r = cell / 9, c = cell % 9;
        const int br = (r / 3) * 3, bc = (c / 3) * 3;
        float acc = 0.0f;
#pragma unroll
        for (int j = 0; j < 9; ++j) acc = fmaf(ps[0][cell][j], bf2f(vs[r * 9 + j][e]), acc);
#pragma unroll
        for (int j = 0; j < 9; ++j) acc = fmaf(ps[1][cell][j], bf2f(vs[j * 9 + c][e]), acc);
#pragma unroll
        for (int j = 0; j < 9; ++j) acc = fmaf(ps[2][cell][j], bf2f(vs[(br + j / 3) * 9 + bc + j % 3][e]), acc);
        y[(long)(b * LL + cell) * DD + h * EE + e] = f2bf(acc * (1.0f / 3.0f));
    }
}

// ---------------- launch ----------------
extern "C" void kernel_launch(void* const* d_in, const int* in_sizes, int n_in,
                              void* d_out, int out_size, void* d_ws, size_t ws_size,
                              hipStream_t stream) {
    const float* src    = (const float*)d_in[0];
    const float* w_qkv  = (const float*)d_in[1];
    const float* b_qkv  = (const float*)d_in[2];
    const float* w_out  = (const float*)d_in[3];
    const float* b_out  = (const float*)d_in[4];
    const float* g1     = (const float*)d_in[5];
    const float* beta1  = (const float*)d_in[6];
    const float* g2     = (const float*)d_in[7];
    const float* beta2  = (const float*)d_in[8];
    const float* w_ff1  = (const float*)d_in[9];
    const float* b_ff1  = (const float*)d_in[10];
    const float* w_ff2  = (const float*)d_in[11];
    const float* b_ff2  = (const float*)d_in[12];
    float* out = (float*)d_out;

    // workspace layout (bytes), all 256-aligned
    char* ws = (char*)d_ws;
    u16* wqkvt = (u16*)(ws + 0);                         // 1536x512 bf16  (1.5 MB)
    u16* woutt = (u16*)(ws + 1572864);                   // 512x512
    u16* wff1t = (u16*)(ws + 2097152);                   // 2048x512
    u16* wff2t = (u16*)(ws + 4194304);                   // 512x2048
    u16* bufA  = (u16*)(ws + 6291456);                   // M x 512 bf16 (85 MB): xln -> y_attn
    u16* bufB  = (u16*)(ws + 6291456 + 84934656ULL);     // M x 1536 bf16 (255 MB): qkv -> hln + h1c
    u16* hln   = bufB;                                   // M x 512 bf16
    u16* h1c   = bufB + (size_t)MM * DD;                 // M x 1024 bf16

    // 1) weights -> bf16, transposed (N x K)
    transpose_w<<<dim3(N3 / 32, DD / 32), 256, 0, stream>>>(w_qkv, wqkvt, DD, N3);
    transpose_w<<<dim3(DD / 32, DD / 32), 256, 0, stream>>>(w_out, woutt, DD, DD);
    transpose_w<<<dim3(FF / 32, DD / 32), 256, 0, stream>>>(w_ff1, wff1t, DD, FF);
    transpose_w<<<dim3(DD / 32, FF / 32), 256, 0, stream>>>(w_ff2, wff2t, FF, DD);

    // 2) LN1: src -> xln (bufA)
    layernorm_k<<<MM / 4, 256, 0, stream>>>(src, g1, beta1, bufA);

    // 3) qkv = xln @ Wqkv + b  (bf16 out, bufB)
    gemm_bt<EPI_BF16_BIAS><<<dim3(N3 / 128, MM / 128), 256, 0, stream>>>(
        bufA, DD, wqkvt, DD, b_qkv, nullptr, bufB, nullptr, N3, DD);

    // 4) factorized attention -> y (bufA)
    attn_k<<<BB * HH, 256, 0, stream>>>(bufB, bufA);

    // 5) x = y @ Wout + b_out + src  (fp32, d_out)
    gemm_bt<EPI_F32_RESID><<<dim3(DD / 128, MM / 128), 256, 0, stream>>>(
        bufA, DD, woutt, DD, b_out, src, nullptr, out, DD, DD);

    // 6) LN2: x -> hln (bufB low region)
    layernorm_k<<<MM / 4, 256, 0, stream>>>(out, g2, beta2, hln);

    // 7) FFN in two F=1024 chunks: d_out += gelu(hln@W1c + b1c) @ W2c (+ b_ff2 on c0)
    for (int c = 0; c < 2; ++c) {
        gemm_bt<EPI_BF16_GELU><<<dim3(1024 / 128, MM / 128), 256, 0, stream>>>(
            hln, DD, wff1t + (size_t)c * 1024 * DD, DD, b_ff1 + c * 1024, nullptr,
            h1c, nullptr, 1024, DD);
        gemm_bt<EPI_F32_ACCUM><<<dim3(DD / 128, MM / 128), 256, 0, stream>>>(
            h1c, 1024, wff2t + (size_t)c * 1024, FF, (c == 0) ? b_ff2 : nullptr, nullptr,
            nullptr, out, DD, 1024);
    }
}

// Round 2
// 1408.072 us; speedup vs baseline: 1.0803x; 1.0803x over previous
//
#include <hip/hip_runtime.h>

// ---------------- dims ----------------
#define BB 1024
#define NN 9
#define LL 81            // 81 cells
#define DD 512
#define HH 8
#define EE 64
#define FF 2048
#define MM (BB*LL)       // 82944 rows
#define N3 (3*DD)        // 1536

typedef unsigned short u16;
typedef __bf16 bf16x8 __attribute__((ext_vector_type(8)));
typedef float f32x4 __attribute__((ext_vector_type(4)));
typedef unsigned short u16x8 __attribute__((ext_vector_type(8)));

__device__ __forceinline__ float bf2f(u16 u) {
    return __uint_as_float(((unsigned int)u) << 16);
}
__device__ __forceinline__ u16 f2bf(float f) {
    unsigned int u = __float_as_uint(f);
    unsigned int r = u + 0x7fffu + ((u >> 16) & 1u);
    return (u16)(r >> 16);
}
__device__ __forceinline__ float gelu_exact(float v) {
    return 0.5f * v * (1.0f + erff(v * 0.70710678118654752f));
}

// async global->LDS, 16B per lane
#define GL16(g, l) __builtin_amdgcn_global_load_lds( \
    (const __attribute__((address_space(1))) void*)(g), \
    (__attribute__((address_space(3))) void*)(l), 16, 0, 0)

// ---------------- weight transpose + fp32->bf16 ----------------
__global__ void transpose_w(const float* __restrict__ W, u16* __restrict__ Wt,
                            int K, int N) {
    __shared__ float t[32][33];
    int n0 = blockIdx.x * 32, k0 = blockIdx.y * 32;
    int tx = threadIdx.x & 31, ty = threadIdx.x >> 5;  // 32 x 8
#pragma unroll
    for (int i = 0; i < 32; i += 8)
        t[ty + i][tx] = W[(long)(k0 + ty + i) * N + n0 + tx];
    __syncthreads();
#pragma unroll
    for (int i = 0; i < 32; i += 8)
        Wt[(long)(n0 + ty + i) * K + k0 + tx] = f2bf(t[tx][ty + i]);
}

// ---------------- layernorm (fp32 in -> bf16 out), one wave per 512-row ----------------
__global__ __launch_bounds__(256) void layernorm_k(const float* __restrict__ X,
                                                   const float* __restrict__ g,
                                                   const float* __restrict__ be,
                                                   u16* __restrict__ Y) {
    int row = blockIdx.x * 4 + (threadIdx.x >> 6);
    int lane = threadIdx.x & 63;
    const float4* xp = (const float4*)(X + (long)row * DD);
    float4 a = xp[lane * 2], b = xp[lane * 2 + 1];
    float s  = a.x + a.y + a.z + a.w + b.x + b.y + b.z + b.w;
    float sq = a.x*a.x + a.y*a.y + a.z*a.z + a.w*a.w
             + b.x*b.x + b.y*b.y + b.z*b.z + b.w*b.w;
#pragma unroll
    for (int off = 1; off < 64; off <<= 1) {
        s  += __shfl_xor(s, off);
        sq += __shfl_xor(sq, off);
    }
    float mean = s * (1.0f / 512.0f);
    float var  = sq * (1.0f / 512.0f) - mean * mean;
    float rstd = rsqrtf(var + 1e-5f);
    const float4* gp = (const float4*)(g + lane * 8);
    const float4* bp = (const float4*)(be + lane * 8);
    float4 g0 = gp[0], g1v = gp[1], b0 = bp[0], b1v = bp[1];
    float xv[8] = {a.x,a.y,a.z,a.w,b.x,b.y,b.z,b.w};
    float gv[8] = {g0.x,g0.y,g0.z,g0.w,g1v.x,g1v.y,g1v.z,g1v.w};
    float bv[8] = {b0.x,b0.y,b0.z,b0.w,b1v.x,b1v.y,b1v.z,b1v.w};
    u16x8 ov;
#pragma unroll
    for (int j = 0; j < 8; ++j)
        ov[j] = f2bf((xv[j] - mean) * rstd * gv[j] + bv[j]);
    *(u16x8*)(Y + (long)row * DD + lane * 8) = ov;
}

// ---------------- GEMM: C = A(bf16, MxK) @ Bt^T(bf16, NxK), m97-style ----------------
enum { EPI_BF16_BIAS = 0, EPI_F32_RESID = 1, EPI_BF16_GELU = 2, EPI_F32_ACCUM = 3 };

template <int EPI>
__global__ __launch_bounds__(256, 2) void gemm_bt(
    const u16* __restrict__ A, int lda,
    const u16* __restrict__ Bt, int ldb,
    const float* __restrict__ bias,   // may be null
    const float* __restrict__ resid,  // EPI_F32_RESID only
    u16* __restrict__ outB, float* __restrict__ outF,
    int N, int K, int nbn) {
    __shared__ u16 As[2][128][32];   // linear: global_load_lds dest (no pad)
    __shared__ u16 Bs[2][128][32];
    const int tid = threadIdx.x;
    const int lane = tid & 63;
    const int w = tid >> 6;
    const int wr = w >> 1, wc = w & 1;

    // bijective XCD-chunked swizzle (all launches have gridDim.x % 8 == 0)
    const int cpx = gridDim.x >> 3;
    const int bid = (blockIdx.x & 7) * cpx + (blockIdx.x >> 3);
    const int bm = bid / nbn, bn = bid % nbn;
    const long Arow0 = (long)bm * 128;
    const long Brow0 = (long)bn * 128;

    // stage one 128x32 K-tile of A and B into buf via global_load_lds(16B).
    // LDS dest is linear chunk c*16B; global source slot is inverse-swizzled
    // (rule #21 both-sides): LDS[row][slot] holds global col (slot^(row&3)).
    auto stage = [&](int buf, int kt) {
        const long ka = (long)kt * 32;
#pragma unroll
        for (int u = 0; u < 2; ++u) {
            const int c = tid + u * 256;       // 512 chunks of 16B
            const int row = c >> 2;
            const int col = ((c & 3) ^ (row & 3)) * 8;
            GL16(A + (Arow0 + row) * (long)lda + ka + col,
                 (u16*)As + (size_t)buf * 4096 + c * 8);
            GL16(Bt + (Brow0 + row) * (long)ldb + ka + col,
                 (u16*)Bs + (size_t)buf * 4096 + c * 8);
        }
    };

    f32x4 acc[4][4] = {};
    const int fr = lane & 15;
    const int sl = ((lane >> 4) ^ (lane & 3)) * 8;  // swizzled 16B slot (row&3 == lane&3)

    const int nk = K / 32;
    stage(0, 0);
    for (int kt = 0; kt < nk; ++kt) {
        const int cur = kt & 1;
        __syncthreads();                 // drains vmcnt -> buf[cur] ready
        if (kt + 1 < nk) stage(cur ^ 1, kt + 1);
        bf16x8 af[4], bb[4];
#pragma unroll
        for (int mt = 0; mt < 4; ++mt)
            af[mt] = *(const bf16x8*)(&As[cur][wr * 64 + mt * 16 + fr][0] + sl);
#pragma unroll
        for (int nt = 0; nt < 4; ++nt)
            bb[nt] = *(const bf16x8*)(&Bs[cur][wc * 64 + nt * 16 + fr][0] + sl);
#pragma unroll
        for (int mt = 0; mt < 4; ++mt)
#pragma unroll
            for (int nt = 0; nt < 4; ++nt)
                acc[mt][nt] = __builtin_amdgcn_mfma_f32_16x16x32_bf16(af[mt], bb[nt], acc[mt][nt], 0, 0, 0);
    }

    // epilogue
    const int col0 = bn * 128 + wc * 64;
    const int row0 = bm * 128 + wr * 64;
#pragma unroll
    for (int nt = 0; nt < 4; ++nt) {
        const int col = col0 + nt * 16 + fr;
        const float bv = bias ? bias[col] : 0.0f;
#pragma unroll
        for (int mt = 0; mt < 4; ++mt) {
            const int rowb = row0 + mt * 16 + ((lane >> 4) * 4);
#pragma unroll
            for (int q = 0; q < 4; ++q) {
                const long idx = (long)(rowb + q) * N + col;
                float v = acc[mt][nt][q] + bv;
                if (EPI == EPI_BF16_BIAS) {
                    outB[idx] = f2bf(v);
                } else if (EPI == EPI_F32_RESID) {
                    outF[idx] = v + resid[idx];
                } else if (EPI == EPI_BF16_GELU) {
                    outB[idx] = f2bf(gelu_exact(v));
                } else {  // EPI_F32_ACCUM
                    outF[idx] += v;
                }
            }
        }
    }
}

// ---------------- factorized attention via MFMA: one block per (b, h) ----------------
// qkv: (B*L, 1536) bf16 ; y: (B*L, 512) bf16
// S = QK^T (96x96 padded); W = dense scatter of 3 row-softmaxes; Y^T = Vt @ W^T.
__global__ __launch_bounds__(256) void attn_k(const u16* __restrict__ qkv,
                                              u16* __restrict__ y) {
    __shared__ u16 S[96][104];    // bf16 scores
    __shared__ u16 Wm[96][104];   // bf16 combined softmax weights (cols 81..95 stay 0)
    __shared__ u16 Vt[64][104];   // V transposed: Vt[e][cell]
    const int bh = blockIdx.x;
    const int b = bh >> 3, h = bh & 7;
    const u16* qbase = qkv + (long)b * LL * N3 + h * EE;
    const u16* kbase = qbase + DD;
    const u16* vbase = qbase + 2 * DD;
    const int tid = threadIdx.x;
    const int lane = tid & 63;
    const int w = tid >> 6;
    const int fr = lane & 15, s8 = lane >> 4;

    // phase 0a: zero Wm, zero Vt pad cols, scatter V -> Vt
    {
        u16x8 z = {};
        u16* wp = &Wm[0][0];
        for (int i = tid; i < (96 * 104) / 8; i += 256)
            *(u16x8*)(wp + i * 8) = z;
        for (int i = tid; i < 64 * 16; i += 256) {
            int e = i >> 4, c = i & 15;
            if (c < 15) Vt[e][81 + c] = 0;
        }
        for (int i = tid; i < 81 * 16; i += 256) {
            int cell = i >> 4, e0 = (i & 15) * 4;
            ushort4 v = *(const ushort4*)(vbase + (long)cell * N3 + e0);
            Vt[e0][cell] = v.x; Vt[e0 + 1][cell] = v.y;
            Vt[e0 + 2][cell] = v.z; Vt[e0 + 3][cell] = v.w;
        }
    }

    // phase 0b: QK^T -> S. 36 tiles of 16x16 over (qcell, kcell), K = e = 64.
    // Fragments load contiguously straight from global qkv (row-major [cell][e]).
    for (int i = 0; i < 9; ++i) {
        const int tile = w + 4 * i;
        const int qt = tile / 6, kt = tile % 6;
        int qc = qt * 16 + fr; if (qc > 80) qc = 80;   // clamp padding rows
        int kc = kt * 16 + fr; if (kc > 80) kc = 80;
        const u16* qp = qbase + (long)qc * N3 + s8 * 8;
        const u16* kp = kbase + (long)kc * N3 + s8 * 8;
        bf16x8 a0 = *(const bf16x8*)qp;
        bf16x8 a1 = *(const bf16x8*)(qp + 32);
        bf16x8 b0 = *(const bf16x8*)kp;
        bf16x8 b1 = *(const bf16x8*)(kp + 32);
        f32x4 acc = {};
        acc = __builtin_amdgcn_mfma_f32_16x16x32_bf16(a0, b0, acc, 0, 0, 0);
        acc = __builtin_amdgcn_mfma_f32_16x16x32_bf16(a1, b1, acc, 0, 0, 0);
#pragma unroll
        for (int q = 0; q < 4; ++q)
            S[qt * 16 + s8 * 4 + q][kt * 16 + fr] = f2bf(acc[q]);
    }
    __syncthreads();

    // phase 1: 3 softmaxes per query row, scatter-add into dense Wm row (no races:
    // thread q exclusively owns row q; overlapping keys accumulate via bf16 RMW).
    if (tid < 81) {
        const int q = tid;
        const int r = q / 9, c = q % 9;
#pragma unroll
        for (int t = 0; t < 3; ++t) {
            int mm[9];
            if (t == 0) {
#pragma unroll
                for (int j = 0; j < 9; ++j) mm[j] = r * 9 + j;
            } else if (t == 1) {
#pragma unroll
                for (int j = 0; j < 9; ++j) mm[j] = j * 9 + c;
            } else {
                const int br = (r / 3) * 3, bc = (c / 3) * 3;
#pragma unroll
                for (int j = 0; j < 9; ++j) mm[j] = (br + j / 3) * 9 + bc + j % 3;
            }
            float sc[9], mx = -1e30f;
#pragma unroll
            for (int j = 0; j < 9; ++j) {
                sc[j] = bf2f(S[q][mm[j]]) * 0.125f;
                mx = fmaxf(mx, sc[j]);
            }
            float sum = 0.0f;
#pragma unroll
            for (int j = 0; j < 9; ++j) { sc[j] = __expf(sc[j] - mx); sum += sc[j]; }
            const float inv = 1.0f / (3.0f * sum);
#pragma unroll
            for (int j = 0; j < 9; ++j) {
                u16* p = &Wm[q][mm[j]];
                *p = f2bf(bf2f(*p) + sc[j] * inv);
            }
        }
    }
    __syncthreads();

    // phase 2: Y^T = Vt(e,cell) @ Wm^T(cell,q). Both operands contiguous in LDS.
    // D: col = q-in-tile (lane&15), rows = e-in-tile -> 4 consecutive e per lane
    // => vectorized 8B stores.
    for (int i = 0; i < 6; ++i) {
        const int tile = w + 4 * i;
        const int qt = tile % 6, et = tile / 6;
        f32x4 acc = {};
#pragma unroll
        for (int kc = 0; kc < 3; ++kc) {
            bf16x8 a  = *(const bf16x8*)&Vt[et * 16 + fr][kc * 32 + s8 * 8];
            bf16x8 bf = *(const bf16x8*)&Wm[qt * 16 + fr][kc * 32 + s8 * 8];
            acc = __builtin_amdgcn_mfma_f32_16x16x32_bf16(a, bf, acc, 0, 0, 0);
        }
        const int q = qt * 16 + fr;
        if (q < 81) {
            ushort4 o;
            o.x = f2bf(acc[0]); o.y = f2bf(acc[1]);
            o.z = f2bf(acc[2]); o.w = f2bf(acc[3]);
            *(ushort4*)(y + (long)(b * LL + q) * DD + h * EE + et * 16 + s8 * 4) = o;
        }
    }
}

// ---------------- launch ----------------
extern "C" void kernel_launch(void* const* d_in, const int* in_sizes, int n_in,
                              void* d_out, int out_size, void* d_ws, size_t ws_size,
                              hipStream_t stream) {
    const float* src    = (const float*)d_in[0];
    const float* w_qkv  = (const float*)d_in[1];
    const float* b_qkv  = (const float*)d_in[2];
    const float* w_out  = (const float*)d_in[3];
    const float* b_out  = (const float*)d_in[4];
    const float* g1     = (const float*)d_in[5];
    const float* beta1  = (const float*)d_in[6];
    const float* g2     = (const float*)d_in[7];
    const float* beta2  = (const float*)d_in[8];
    const float* w_ff1  = (const float*)d_in[9];
    const float* b_ff1  = (const float*)d_in[10];
    const float* w_ff2  = (const float*)d_in[11];
    const float* b_ff2  = (const float*)d_in[12];
    float* out = (float*)d_out;

    // workspace layout (bytes), all 256-aligned
    char* ws = (char*)d_ws;
    u16* wqkvt = (u16*)(ws + 0);                         // 1536x512 bf16
    u16* woutt = (u16*)(ws + 1572864);                   // 512x512
    u16* wff1t = (u16*)(ws + 2097152);                   // 2048x512
    u16* wff2t = (u16*)(ws + 4194304);                   // 512x2048
    u16* bufA  = (u16*)(ws + 6291456);                   // M x 512 bf16: xln -> y_attn
    u16* bufB  = (u16*)(ws + 6291456 + 84934656ULL);     // M x 1536 bf16: qkv -> hln + h1c
    u16* hln   = bufB;                                   // M x 512 bf16
    u16* h1c   = bufB + (size_t)MM * DD;                 // M x 1024 bf16

    const int nbm = MM / 128;  // 648

    // 1) weights -> bf16, transposed (N x K)
    transpose_w<<<dim3(N3 / 32, DD / 32), 256, 0, stream>>>(w_qkv, wqkvt, DD, N3);
    transpose_w<<<dim3(DD / 32, DD / 32), 256, 0, stream>>>(w_out, woutt, DD, DD);
    transpose_w<<<dim3(FF / 32, DD / 32), 256, 0, stream>>>(w_ff1, wff1t, DD, FF);
    transpose_w<<<dim3(DD / 32, FF / 32), 256, 0, stream>>>(w_ff2, wff2t, FF, DD);

    // 2) LN1: src -> xln (bufA)
    layernorm_k<<<MM / 4, 256, 0, stream>>>(src, g1, beta1, bufA);

    // 3) qkv = xln @ Wqkv + b  (bf16 out, bufB)
    gemm_bt<EPI_BF16_BIAS><<<nbm * (N3 / 128), 256, 0, stream>>>(
        bufA, DD, wqkvt, DD, b_qkv, nullptr, bufB, nullptr, N3, DD, N3 / 128);

    // 4) factorized attention -> y (bufA)
    attn_k<<<BB * HH, 256, 0, stream>>>(bufB, bufA);

    // 5) x = y @ Wout + b_out + src  (fp32, d_out)
    gemm_bt<EPI_F32_RESID><<<nbm * (DD / 128), 256, 0, stream>>>(
        bufA, DD, woutt, DD, b_out, src, nullptr, out, DD, DD, DD / 128);

    // 6) LN2: x -> hln
    layernorm_k<<<MM / 4, 256, 0, stream>>>(out, g2, beta2, hln);

    // 7) FFN in two F=1024 chunks: d_out += gelu(hln@W1c + b1c) @ W2c
    for (int c = 0; c < 2; ++c) {
        gemm_bt<EPI_BF16_GELU><<<nbm * (1024 / 128), 256, 0, stream>>>(
            hln, DD, wff1t + (size_t)c * 1024 * DD, DD, b_ff1 + c * 1024, nullptr,
            h1c, nullptr, 1024, DD, 1024 / 128);
        gemm_bt<EPI_F32_ACCUM><<<nbm * (DD / 128), 256, 0, stream>>>(
            h1c, 1024, wff2t + (size_t)c * 1024, FF, (c == 0) ? b_ff2 : nullptr, nullptr,
            nullptr, out, DD, 1024, DD / 128);
    }
}

// Round 3
// 1213.324 us; speedup vs baseline: 1.2537x; 1.1605x over previous
//
#include <hip/hip_runtime.h>

// ---------------- dims ----------------
#define BB 1024
#define NN 9
#define LL 81            // 81 cells
#define DD 512
#define HH 8
#define EE 64
#define FF 2048
#define MM (BB*LL)       // 82944 rows
#define N3 (3*DD)        // 1536

typedef unsigned short u16;
typedef __bf16 bf16x8 __attribute__((ext_vector_type(8)));
typedef float f32x4 __attribute__((ext_vector_type(4)));
typedef unsigned short u16x8 __attribute__((ext_vector_type(8)));

__device__ __forceinline__ float bf2f(u16 u) {
    return __uint_as_float(((unsigned int)u) << 16);
}
__device__ __forceinline__ u16 f2bf(float f) {
    unsigned int u = __float_as_uint(f);
    unsigned int r = u + 0x7fffu + ((u >> 16) & 1u);
    return (u16)(r >> 16);
}
__device__ __forceinline__ float gelu_exact(float v) {
    return 0.5f * v * (1.0f + erff(v * 0.70710678118654752f));
}

// async global->LDS, 16B per lane
#define GL16(g, l) __builtin_amdgcn_global_load_lds( \
    (const __attribute__((address_space(1))) void*)(g), \
    (__attribute__((address_space(3))) void*)(l), 16, 0, 0)

// ---------------- weight transpose + fp32->bf16 ----------------
__global__ void transpose_w(const float* __restrict__ W, u16* __restrict__ Wt,
                            int K, int N) {
    __shared__ float t[32][33];
    int n0 = blockIdx.x * 32, k0 = blockIdx.y * 32;
    int tx = threadIdx.x & 31, ty = threadIdx.x >> 5;  // 32 x 8
#pragma unroll
    for (int i = 0; i < 32; i += 8)
        t[ty + i][tx] = W[(long)(k0 + ty + i) * N + n0 + tx];
    __syncthreads();
#pragma unroll
    for (int i = 0; i < 32; i += 8)
        Wt[(long)(n0 + ty + i) * K + k0 + tx] = f2bf(t[tx][ty + i]);
}

// ---------------- layernorm (fp32 in -> bf16 out), one wave per 512-row ----------------
__global__ __launch_bounds__(256) void layernorm_k(const float* __restrict__ X,
                                                   const float* __restrict__ g,
                                                   const float* __restrict__ be,
                                                   u16* __restrict__ Y) {
    int row = blockIdx.x * 4 + (threadIdx.x >> 6);
    int lane = threadIdx.x & 63;
    const float4* xp = (const float4*)(X + (long)row * DD);
    float4 a = xp[lane * 2], b = xp[lane * 2 + 1];
    float s  = a.x + a.y + a.z + a.w + b.x + b.y + b.z + b.w;
    float sq = a.x*a.x + a.y*a.y + a.z*a.z + a.w*a.w
             + b.x*b.x + b.y*b.y + b.z*b.z + b.w*b.w;
#pragma unroll
    for (int off = 1; off < 64; off <<= 1) {
        s  += __shfl_xor(s, off);
        sq += __shfl_xor(sq, off);
    }
    float mean = s * (1.0f / 512.0f);
    float var  = sq * (1.0f / 512.0f) - mean * mean;
    float rstd = rsqrtf(var + 1e-5f);
    const float4* gp = (const float4*)(g + lane * 8);
    const float4* bp = (const float4*)(be + lane * 8);
    float4 g0 = gp[0], g1v = gp[1], b0 = bp[0], b1v = bp[1];
    float xv[8] = {a.x,a.y,a.z,a.w,b.x,b.y,b.z,b.w};
    float gv[8] = {g0.x,g0.y,g0.z,g0.w,g1v.x,g1v.y,g1v.z,g1v.w};
    float bv[8] = {b0.x,b0.y,b0.z,b0.w,b1v.x,b1v.y,b1v.z,b1v.w};
    u16x8 ov;
#pragma unroll
    for (int j = 0; j < 8; ++j)
        ov[j] = f2bf((xv[j] - mean) * rstd * gv[j] + bv[j]);
    *(u16x8*)(Y + (long)row * DD + lane * 8) = ov;
}

// ---------------- GEMM: C = A(bf16, MxK) @ Bt^T(bf16, NxK) ----------------
// 128x128 tile, BK=32, 3-buffer counted-vmcnt pipeline (T4), LDS slot-swizzle (T2,
// both-sides per rule #21), XCD-chunked block swizzle (T1), LDS-bounce bf16 epilogue.
enum { EPI_BF16_BIAS = 0, EPI_F32_RESID = 1, EPI_BF16_GELU = 2, EPI_F32_ACCUM = 3 };

template <int EPI>
__global__ __launch_bounds__(256, 2) void gemm_bt(
    const u16* __restrict__ A, int lda,
    const u16* __restrict__ Bt, int ldb,
    const float* __restrict__ bias,   // may be null
    const float* __restrict__ resid,  // EPI_F32_RESID only
    u16* __restrict__ outB, float* __restrict__ outF,
    int N, int K, int nbn) {
    __shared__ u16 smem[24576];            // 48KB: 3x(As 8KB) + 3x(Bs 8KB); epilogue bounce aliases
    u16* const Asb = smem;                 // buf b at Asb + b*4096
    u16* const Bsb = smem + 12288;
    const int tid = threadIdx.x;
    const int lane = tid & 63;
    const int w = tid >> 6;
    const int wr = w >> 1, wc = w & 1;

    // bijective XCD-chunked swizzle (all launches have gridDim.x % 8 == 0)
    const int cpx = gridDim.x >> 3;
    const int bid = (blockIdx.x & 7) * cpx + (blockIdx.x >> 3);
    const int bm = bid / nbn, bn = bid % nbn;
    const long Arow0 = (long)bm * 128;
    const long Brow0 = (long)bn * 128;

    // stage one 128x32 K-tile of A and B (4 GL16 per thread). LDS dest linear;
    // global source slot inverse-swizzled: LDS[row][slot] = global col (slot^(row&3)).
    auto stage = [&](int buf, int kt) {
        const u16* abase = A + Arow0 * (long)lda + (long)kt * 32;
        const u16* bbase = Bt + Brow0 * (long)ldb + (long)kt * 32;
#pragma unroll
        for (int u = 0; u < 2; ++u) {
            const int c = tid + u * 256;       // 512 chunks of 16B each for A and B
            const int row = c >> 2;
            const int col = ((c & 3) ^ (row & 3)) * 8;
            GL16(abase + (long)row * lda + col, Asb + buf * 4096 + c * 8);
            GL16(bbase + (long)row * ldb + col, Bsb + buf * 4096 + c * 8);
        }
    };

    f32x4 acc[4][4] = {};
    const int fr = lane & 15;
    const int sl = ((lane >> 4) ^ (lane & 3)) * 8;  // swizzled 16B slot (row&3 == lane&3)

    const int nk = K / 32;                 // >= 16 for all our shapes
    stage(0, 0); stage(1, 1); stage(2, 2); // 12 GL16/thread in flight

    int cur = 0;
    for (int kt = 0; kt < nk; ++kt) {
        // wait for buf[cur]'s 4 loads; keep later tiles' loads in flight (never drain mid-loop)
        if (kt + 2 < nk)      { asm volatile("s_waitcnt vmcnt(8)" ::: "memory"); }
        else if (kt + 1 < nk) { asm volatile("s_waitcnt vmcnt(4)" ::: "memory"); }
        else                  { asm volatile("s_waitcnt vmcnt(0)" ::: "memory"); }
        __builtin_amdgcn_sched_barrier(0);
        __builtin_amdgcn_s_barrier();      // all waves' slices of buf[cur] landed

        bf16x8 af[4], bb[4];
        const u16* Ab = Asb + cur * 4096;
        const u16* Bb = Bsb + cur * 4096;
#pragma unroll
        for (int mt = 0; mt < 4; ++mt)
            af[mt] = *(const bf16x8*)(Ab + (wr * 64 + mt * 16 + fr) * 32 + sl);
#pragma unroll
        for (int nt = 0; nt < 4; ++nt)
            bb[nt] = *(const bf16x8*)(Bb + (wc * 64 + nt * 16 + fr) * 32 + sl);
        asm volatile("s_waitcnt lgkmcnt(0)" ::: "memory");
        __builtin_amdgcn_sched_barrier(0); // rule #18: keep MFMAs below the wait
        __builtin_amdgcn_s_barrier();      // all waves done reading buf[cur]

        if (kt + 3 < nk) stage(cur, kt + 3);   // overwrite just-consumed buffer

#pragma unroll
        for (int mt = 0; mt < 4; ++mt)
#pragma unroll
            for (int nt = 0; nt < 4; ++nt)
                acc[mt][nt] = __builtin_amdgcn_mfma_f32_16x16x32_bf16(af[mt], bb[nt], acc[mt][nt], 0, 0, 0);
        cur = cur + 1; if (cur == 3) cur = 0;
    }

    const int s8 = lane >> 4;
    if (EPI == EPI_BF16_BIAS || EPI == EPI_BF16_GELU) {
        // LDS-bounce epilogue: pad stride 132 -> the 4 s8-row-groups hit disjoint banks
        u16 (*eps)[132] = (u16(*)[132])smem;
#pragma unroll
        for (int nt = 0; nt < 4; ++nt) {
            const int cl = wc * 64 + nt * 16 + fr;
            const float bv = bias ? bias[bn * 128 + cl] : 0.0f;
#pragma unroll
            for (int mt = 0; mt < 4; ++mt) {
                const int rl = wr * 64 + mt * 16 + s8 * 4;
#pragma unroll
                for (int q = 0; q < 4; ++q) {
                    float v = acc[mt][nt][q] + bv;
                    if (EPI == EPI_BF16_GELU) v = gelu_exact(v);
                    eps[rl + q][cl] = f2bf(v);
                }
            }
        }
        __syncthreads();
#pragma unroll
        for (int u = 0; u < 8; ++u) {
            const int i = u * 256 + tid;
            const int row = i >> 4, cc = (i & 15) * 8;
            u16x8 vv = *(const u16x8*)&eps[row][cc];
            *(u16x8*)(outB + (Arow0 + row) * (long)N + bn * 128 + cc) = vv;
        }
    } else {
        const int col0 = bn * 128 + wc * 64;
        const int row0 = bm * 128 + wr * 64;
#pragma unroll
        for (int nt = 0; nt < 4; ++nt) {
            const int col = col0 + nt * 16 + fr;
            const float bv = bias ? bias[col] : 0.0f;
#pragma unroll
            for (int mt = 0; mt < 4; ++mt) {
                const int rowb = row0 + mt * 16 + s8 * 4;
#pragma unroll
                for (int q = 0; q < 4; ++q) {
                    const long idx = (long)(rowb + q) * N + col;
                    float v = acc[mt][nt][q] + bv;
                    if (EPI == EPI_F32_RESID) outF[idx] = v + resid[idx];
                    else                      outF[idx] += v;   // EPI_F32_ACCUM
                }
            }
        }
    }
}

// ---------------- factorized attention via MFMA: one block per (b, h) ----------------
__global__ __launch_bounds__(256) void attn_k(const u16* __restrict__ qkv,
                                              u16* __restrict__ y) {
    __shared__ u16 S[96][104];    // bf16 scores
    __shared__ u16 Wm[96][104];   // bf16 combined softmax weights (cols 81..95 stay 0)
    __shared__ u16 Vt[64][104];   // V transposed: Vt[e][cell]
    const int bh = blockIdx.x;
    const int b = bh >> 3, h = bh & 7;
    const u16* qbase = qkv + (long)b * LL * N3 + h * EE;
    const u16* kbase = qbase + DD;
    const u16* vbase = qbase + 2 * DD;
    const int tid = threadIdx.x;
    const int lane = tid & 63;
    const int w = tid >> 6;
    const int fr = lane & 15, s8 = lane >> 4;

    // phase 0a: zero Wm, zero Vt pad cols, scatter V -> Vt
    {
        u16x8 z = {};
        u16* wp = &Wm[0][0];
        for (int i = tid; i < (96 * 104) / 8; i += 256)
            *(u16x8*)(wp + i * 8) = z;
        for (int i = tid; i < 64 * 16; i += 256) {
            int e = i >> 4, c = i & 15;
            if (c < 15) Vt[e][81 + c] = 0;
        }
        for (int i = tid; i < 81 * 16; i += 256) {
            int cell = i >> 4, e0 = (i & 15) * 4;
            ushort4 v = *(const ushort4*)(vbase + (long)cell * N3 + e0);
            Vt[e0][cell] = v.x; Vt[e0 + 1][cell] = v.y;
            Vt[e0 + 2][cell] = v.z; Vt[e0 + 3][cell] = v.w;
        }
    }

    // phase 0b: QK^T -> S. 36 tiles of 16x16, K = 64; frags straight from global.
    for (int i = 0; i < 9; ++i) {
        const int tile = w + 4 * i;
        const int qt = tile / 6, kt = tile % 6;
        int qc = qt * 16 + fr; if (qc > 80) qc = 80;
        int kc = kt * 16 + fr; if (kc > 80) kc = 80;
        const u16* qp = qbase + (long)qc * N3 + s8 * 8;
        const u16* kp = kbase + (long)kc * N3 + s8 * 8;
        bf16x8 a0 = *(const bf16x8*)qp;
        bf16x8 a1 = *(const bf16x8*)(qp + 32);
        bf16x8 b0 = *(const bf16x8*)kp;
        bf16x8 b1 = *(const bf16x8*)(kp + 32);
        f32x4 acc = {};
        acc = __builtin_amdgcn_mfma_f32_16x16x32_bf16(a0, b0, acc, 0, 0, 0);
        acc = __builtin_amdgcn_mfma_f32_16x16x32_bf16(a1, b1, acc, 0, 0, 0);
#pragma unroll
        for (int q = 0; q < 4; ++q)
            S[qt * 16 + s8 * 4 + q][kt * 16 + fr] = f2bf(acc[q]);
    }
    __syncthreads();

    // phase 1: 3 softmaxes per query row, scatter-add into dense Wm row
    if (tid < 81) {
        const int q = tid;
        const int r = q / 9, c = q % 9;
#pragma unroll
        for (int t = 0; t < 3; ++t) {
            int mm[9];
            if (t == 0) {
#pragma unroll
                for (int j = 0; j < 9; ++j) mm[j] = r * 9 + j;
            } else if (t == 1) {
#pragma unroll
                for (int j = 0; j < 9; ++j) mm[j] = j * 9 + c;
            } else {
                const int br = (r / 3) * 3, bc = (c / 3) * 3;
#pragma unroll
                for (int j = 0; j < 9; ++j) mm[j] = (br + j / 3) * 9 + bc + j % 3;
            }
            float sc[9], mx = -1e30f;
#pragma unroll
            for (int j = 0; j < 9; ++j) {
                sc[j] = bf2f(S[q][mm[j]]) * 0.125f;
                mx = fmaxf(mx, sc[j]);
            }
            float sum = 0.0f;
#pragma unroll
            for (int j = 0; j < 9; ++j) { sc[j] = __expf(sc[j] - mx); sum += sc[j]; }
            const float inv = 1.0f / (3.0f * sum);
#pragma unroll
            for (int j = 0; j < 9; ++j) {
                u16* p = &Wm[q][mm[j]];
                *p = f2bf(bf2f(*p) + sc[j] * inv);
            }
        }
    }
    __syncthreads();

    // phase 2: Y^T = Vt(e,cell) @ Wm^T(cell,q); vectorized 8B stores
    for (int i = 0; i < 6; ++i) {
        const int tile = w + 4 * i;
        const int qt = tile % 6, et = tile / 6;
        f32x4 acc = {};
#pragma unroll
        for (int kc = 0; kc < 3; ++kc) {
            bf16x8 a  = *(const bf16x8*)&Vt[et * 16 + fr][kc * 32 + s8 * 8];
            bf16x8 bf = *(const bf16x8*)&Wm[qt * 16 + fr][kc * 32 + s8 * 8];
            acc = __builtin_amdgcn_mfma_f32_16x16x32_bf16(a, bf, acc, 0, 0, 0);
        }
        const int q = qt * 16 + fr;
        if (q < 81) {
            ushort4 o;
            o.x = f2bf(acc[0]); o.y = f2bf(acc[1]);
            o.z = f2bf(acc[2]); o.w = f2bf(acc[3]);
            *(ushort4*)(y + (long)(b * LL + q) * DD + h * EE + et * 16 + s8 * 4) = o;
        }
    }
}

// ---------------- launch ----------------
extern "C" void kernel_launch(void* const* d_in, const int* in_sizes, int n_in,
                              void* d_out, int out_size, void* d_ws, size_t ws_size,
                              hipStream_t stream) {
    const float* src    = (const float*)d_in[0];
    const float* w_qkv  = (const float*)d_in[1];
    const float* b_qkv  = (const float*)d_in[2];
    const float* w_out  = (const float*)d_in[3];
    const float* b_out  = (const float*)d_in[4];
    const float* g1     = (const float*)d_in[5];
    const float* beta1  = (const float*)d_in[6];
    const float* g2     = (const float*)d_in[7];
    const float* beta2  = (const float*)d_in[8];
    const float* w_ff1  = (const float*)d_in[9];
    const float* b_ff1  = (const float*)d_in[10];
    const float* w_ff2  = (const float*)d_in[11];
    const float* b_ff2  = (const float*)d_in[12];
    float* out = (float*)d_out;

    // workspace layout (bytes), all 256-aligned
    char* ws = (char*)d_ws;
    u16* wqkvt = (u16*)(ws + 0);                         // 1536x512 bf16
    u16* woutt = (u16*)(ws + 1572864);                   // 512x512
    u16* wff1t = (u16*)(ws + 2097152);                   // 2048x512
    u16* wff2t = (u16*)(ws + 4194304);                   // 512x2048
    u16* bufA  = (u16*)(ws + 6291456);                   // M x 512 bf16: xln -> y_attn
    u16* bufB  = (u16*)(ws + 6291456 + 84934656ULL);     // M x 1536 bf16: qkv -> hln + h1
    u16* hln   = bufB;                                   // M x 512 bf16 (LN2 out)
    u16* h1    = bufB + (size_t)MM * DD;                 // (M/2) x 2048 bf16 (per-half GELU buf)

    const int nbm = MM / 128;       // 648
    const int nbmh = (MM / 2) / 128; // 324

    // 1) weights -> bf16, transposed (N x K)
    transpose_w<<<dim3(N3 / 32, DD / 32), 256, 0, stream>>>(w_qkv, wqkvt, DD, N3);
    transpose_w<<<dim3(DD / 32, DD / 32), 256, 0, stream>>>(w_out, woutt, DD, DD);
    transpose_w<<<dim3(FF / 32, DD / 32), 256, 0, stream>>>(w_ff1, wff1t, DD, FF);
    transpose_w<<<dim3(DD / 32, FF / 32), 256, 0, stream>>>(w_ff2, wff2t, FF, DD);

    // 2) LN1: src -> xln (bufA)
    layernorm_k<<<MM / 4, 256, 0, stream>>>(src, g1, beta1, bufA);

    // 3) qkv = xln @ Wqkv + b  (bf16 out, bufB)
    gemm_bt<EPI_BF16_BIAS><<<nbm * (N3 / 128), 256, 0, stream>>>(
        bufA, DD, wqkvt, DD, b_qkv, nullptr, bufB, nullptr, N3, DD, N3 / 128);

    // 4) factorized attention -> y (bufA)
    attn_k<<<BB * HH, 256, 0, stream>>>(bufB, bufA);

    // 5) x = y @ Wout + b_out + src  (fp32, d_out)
    gemm_bt<EPI_F32_RESID><<<nbm * (DD / 128), 256, 0, stream>>>(
        bufA, DD, woutt, DD, b_out, src, nullptr, out, DD, DD, DD / 128);

    // 6) LN2: x -> hln
    layernorm_k<<<MM / 4, 256, 0, stream>>>(out, g2, beta2, hln);

    // 7) FFN split by M-halves: full F=2048 GELU buffer per half, single K=2048 ff2
    for (int mh = 0; mh < 2; ++mh) {
        const size_t roff = (size_t)mh * (MM / 2);
        gemm_bt<EPI_BF16_GELU><<<nbmh * (FF / 128), 256, 0, stream>>>(
            hln + roff * DD, DD, wff1t, DD, b_ff1, nullptr,
            h1, nullptr, FF, DD, FF / 128);
        gemm_bt<EPI_F32_ACCUM><<<nbmh * (DD / 128), 256, 0, stream>>>(
            h1, FF, wff2t, FF, b_ff2, nullptr,
            nullptr, out + roff * DD, DD, FF, DD / 128);
    }
}